// Round 1
// baseline (672.929 us; speedup 1.0000x reference)
//
#include <hip/hip_runtime.h>
#include <math.h>

#define S_LEN 4096
#define N_STR 4
#define D_DIM 1024
#define ND    4096   // N_STR * D_DIM (flattened stream*dim)
#define ND4   1024   // ND / 4
#define SCHUNK 64
#define CHUNKS 64    // S_LEN / SCHUNK

// ---------------- Kernel 1: partial mean over S ----------------
// grid = B(4) * CHUNKS(64) * dq(4) = 1024 blocks, 256 threads.
// Each block sums SCHUNK consecutive s values for a 256-float4 slice of the
// (n*D) inner dim, writing one partial vector per (b, chunk).
__global__ __launch_bounds__(256) void k1_reduce(const float4* __restrict__ H4,
                                                 float4* __restrict__ partial4) {
  int blk = blockIdx.x;
  int b = blk >> 8;
  int chunk = (blk >> 2) & 63;
  int dq = blk & 3;
  int fidx = dq * 256 + threadIdx.x;                  // float4 index in [0, ND4)
  const float4* p = H4 + ((size_t)(b * S_LEN + chunk * SCHUNK)) * ND4 + fidx;
  float4 acc = make_float4(0.f, 0.f, 0.f, 0.f);
#pragma unroll 4
  for (int s = 0; s < SCHUNK; ++s) {
    float4 v = p[(size_t)s * ND4];
    acc.x += v.x; acc.y += v.y; acc.z += v.z; acc.w += v.w;
  }
  partial4[((size_t)(b * CHUNKS + chunk)) * ND4 + fidx] = acc;
}

// ---------------- Kernel 2: stats + gates + sinkhorn ----------------
// grid = B (4 blocks), 256 threads. Produces weights[b*24 + {0..3 H_pre,
// 4..7 H_post, 8..23 H_res}].
__global__ __launch_bounds__(256) void k2_stats(
    const float4* __restrict__ partial4, const float* __restrict__ phi,
    const float* __restrict__ hpre_b, const float* __restrict__ hpost_b,
    const float* __restrict__ hres_b, const float* __restrict__ a_pre_p,
    const float* __restrict__ a_post_p, const float* __restrict__ a_res_p,
    float* __restrict__ weights) {
  int b = blockIdx.x;
  int tid = threadIdx.x;
  __shared__ float xs[ND];        // mean vector (already / S)
  __shared__ float ssq_s;
  __shared__ float s_inv_rms;
  __shared__ float delta_s[24];

  if (tid == 0) ssq_s = 0.f;
  if (tid < 24) delta_s[tid] = 0.f;
  __syncthreads();

  float ssq = 0.f;
  const float inv_s = 1.0f / (float)S_LEN;
#pragma unroll
  for (int k = 0; k < 4; ++k) {
    int fidx = tid + k * 256;
    float4 acc = make_float4(0.f, 0.f, 0.f, 0.f);
    for (int c = 0; c < CHUNKS; ++c) {
      float4 v = partial4[((size_t)(b * CHUNKS + c)) * ND4 + fidx];
      acc.x += v.x; acc.y += v.y; acc.z += v.z; acc.w += v.w;
    }
    acc.x *= inv_s; acc.y *= inv_s; acc.z *= inv_s; acc.w *= inv_s;
    xs[fidx * 4 + 0] = acc.x;
    xs[fidx * 4 + 1] = acc.y;
    xs[fidx * 4 + 2] = acc.z;
    xs[fidx * 4 + 3] = acc.w;
    ssq += acc.x * acc.x + acc.y * acc.y + acc.z * acc.z + acc.w * acc.w;
  }
  atomicAdd(&ssq_s, ssq);
  __syncthreads();
  if (tid == 0) {
    s_inv_rms = 1.0f / sqrtf(ssq_s * (1.0f / (float)ND) + 1e-6f);
  }
  __syncthreads();

  // delta_k = (sum_i x_i * phi[i,k]) * inv_rms, k in [0,24)
  float acc[24];
#pragma unroll
  for (int m = 0; m < 24; ++m) acc[m] = 0.f;
  for (int k = 0; k < 16; ++k) {
    int i = tid + k * 256;
    float xv = xs[i];
    const float* ph = phi + (size_t)i * 24;
#pragma unroll
    for (int m = 0; m < 24; ++m) acc[m] = fmaf(xv, ph[m], acc[m]);
  }
#pragma unroll
  for (int m = 0; m < 24; ++m) atomicAdd(&delta_s[m], acc[m]);
  __syncthreads();

  if (tid == 0) {
    float inv_rms = s_inv_rms;
    float a_pre = a_pre_p[0], a_post = a_post_p[0], a_res = a_res_p[0];
    float d[24];
#pragma unroll
    for (int m = 0; m < 24; ++m) d[m] = delta_s[m] * inv_rms;

    // H_pre: sigmoid then normalize
    float hp[4], hsum = 0.f;
#pragma unroll
    for (int k = 0; k < 4; ++k) {
      hp[k] = 1.0f / (1.0f + expf(-(hpre_b[k] + a_pre * d[k])));
      hsum += hp[k];
    }
    float invsum = 1.0f / (hsum + 1e-8f);
#pragma unroll
    for (int k = 0; k < 4; ++k) weights[b * 24 + k] = hp[k] * invsum;

    // H_post: sigmoid
#pragma unroll
    for (int k = 0; k < 4; ++k)
      weights[b * 24 + 4 + k] =
          1.0f / (1.0f + expf(-(hpost_b[k] + a_post * d[4 + k])));

    // Sinkhorn on 4x4
    float P[16];
#pragma unroll
    for (int e = 0; e < 16; ++e) P[e] = expf(hres_b[e] + a_res * d[8 + e]);
    for (int it = 0; it < 20; ++it) {
#pragma unroll
      for (int i = 0; i < 4; ++i) {
        float rs = P[i * 4] + P[i * 4 + 1] + P[i * 4 + 2] + P[i * 4 + 3];
        float inv = 1.0f / (rs + 1e-6f);
        P[i * 4] *= inv; P[i * 4 + 1] *= inv; P[i * 4 + 2] *= inv; P[i * 4 + 3] *= inv;
      }
#pragma unroll
      for (int j = 0; j < 4; ++j) {
        float cs = P[j] + P[4 + j] + P[8 + j] + P[12 + j];
        float inv = 1.0f / (cs + 1e-6f);
        P[j] *= inv; P[4 + j] *= inv; P[8 + j] *= inv; P[12 + j] *= inv;
      }
    }
#pragma unroll
    for (int e = 0; e < 16; ++e) weights[b * 24 + 8 + e] = P[e];
  }
}

// ---------------- Kernel 3: apply gates ----------------
// grid = B*S = 16384 blocks, 256 threads, one float4 of D per thread.
__global__ __launch_bounds__(256) void k3_apply(const float4* __restrict__ H4,
                                                const float4* __restrict__ BO4,
                                                const float* __restrict__ weights,
                                                float4* __restrict__ out4) {
  int bs = blockIdx.x;            // b * S + s
  int b = bs >> 12;
  __shared__ float w[24];
  if (threadIdx.x < 24) w[threadIdx.x] = weights[b * 24 + threadIdx.x];
  __syncthreads();
  int t = threadIdx.x;            // [0,256): float4 index within D
  const float4* hb = H4 + (size_t)bs * ND4;
  float4 h0 = hb[t];
  float4 h1 = hb[256 + t];
  float4 h2 = hb[512 + t];
  float4 h3 = hb[768 + t];
  float4 bo = BO4[(size_t)bs * 256 + t];
  float4* ob = out4 + (size_t)bs * (5 * 256);

  float4 o;
  // channel 0: branch_input = sum_k H_pre[k] * H[..,k,..]
  o.x = w[0] * h0.x + w[1] * h1.x + w[2] * h2.x + w[3] * h3.x;
  o.y = w[0] * h0.y + w[1] * h1.y + w[2] * h2.y + w[3] * h3.y;
  o.z = w[0] * h0.z + w[1] * h1.z + w[2] * h2.z + w[3] * h3.z;
  o.w = w[0] * h0.w + w[1] * h1.w + w[2] * h2.w + w[3] * h3.w;
  ob[t] = o;

#pragma unroll
  for (int i = 0; i < 4; ++i) {
    float w0 = w[8 + i * 4 + 0];
    float w1 = w[8 + i * 4 + 1];
    float w2 = w[8 + i * 4 + 2];
    float w3 = w[8 + i * 4 + 3];
    float wp = w[4 + i];
    o.x = w0 * h0.x + w1 * h1.x + w2 * h2.x + w3 * h3.x + wp * bo.x;
    o.y = w0 * h0.y + w1 * h1.y + w2 * h2.y + w3 * h3.y + wp * bo.y;
    o.z = w0 * h0.z + w1 * h1.z + w2 * h2.z + w3 * h3.z + wp * bo.z;
    o.w = w0 * h0.w + w1 * h1.w + w2 * h2.w + w3 * h3.w + wp * bo.w;
    ob[(i + 1) * 256 + t] = o;
  }
}

extern "C" void kernel_launch(void* const* d_in, const int* in_sizes, int n_in,
                              void* d_out, int out_size, void* d_ws, size_t ws_size,
                              hipStream_t stream) {
  const float* H       = (const float*)d_in[0];
  const float* BO      = (const float*)d_in[1];
  const float* phi     = (const float*)d_in[2];
  const float* hpre_b  = (const float*)d_in[3];
  const float* hpost_b = (const float*)d_in[4];
  const float* hres_b  = (const float*)d_in[5];
  const float* a_pre   = (const float*)d_in[6];
  const float* a_post  = (const float*)d_in[7];
  const float* a_res   = (const float*)d_in[8];
  float* out = (float*)d_out;

  const size_t partial_floats = (size_t)4 * CHUNKS * ND;  // 1,048,576 (4 MB)
  float* partial;
  float* weights;
  if (ws_size >= (partial_floats + 96) * sizeof(float)) {
    partial = (float*)d_ws;
    weights = partial + partial_floats;
  } else {
    // Fallback: use the (later fully overwritten) output buffer for partials;
    // weights must NOT live in d_out (k3 reads them while writing d_out).
    partial = out;
    weights = (float*)d_ws;  // needs only 384 B
  }

  hipLaunchKernelGGL(k1_reduce, dim3(1024), dim3(256), 0, stream,
                     (const float4*)H, (float4*)partial);
  hipLaunchKernelGGL(k2_stats, dim3(4), dim3(256), 0, stream,
                     (const float4*)partial, phi, hpre_b, hpost_b, hres_b,
                     a_pre, a_post, a_res, weights);
  hipLaunchKernelGGL(k3_apply, dim3(4 * S_LEN), dim3(256), 0, stream,
                     (const float4*)H, (const float4*)BO, weights, (float4*)out);
}

// Round 2
// 610.304 us; speedup vs baseline: 1.1026x; 1.1026x over previous
//
#include <hip/hip_runtime.h>
#include <math.h>

typedef float v4f __attribute__((ext_vector_type(4)));

#define S_LEN 4096
#define ND    4096   // N_STREAMS * D
#define ND4   1024   // ND / 4
#define SCHUNK 64
#define CHUNKS 64    // S_LEN / SCHUNK

// ---------------- Kernel 1: partial sum over S ----------------
// grid = B(4) * CHUNKS(64) * dq(4) = 1024 blocks, 256 threads.
__global__ __launch_bounds__(256) void k1_reduce(const v4f* __restrict__ H4,
                                                 v4f* __restrict__ partial4) {
  int blk = blockIdx.x;
  int b = blk >> 8;
  int chunk = (blk >> 2) & 63;
  int dq = blk & 3;
  int fidx = dq * 256 + threadIdx.x;                  // float4 index in [0, ND4)
  const v4f* p = H4 + ((size_t)(b * S_LEN + chunk * SCHUNK)) * ND4 + fidx;
  v4f a0 = {0.f, 0.f, 0.f, 0.f};
  v4f a1 = {0.f, 0.f, 0.f, 0.f};
  v4f a2 = {0.f, 0.f, 0.f, 0.f};
  v4f a3 = {0.f, 0.f, 0.f, 0.f};
#pragma unroll 4
  for (int s = 0; s < SCHUNK; s += 4) {
    a0 += p[(size_t)(s + 0) * ND4];
    a1 += p[(size_t)(s + 1) * ND4];
    a2 += p[(size_t)(s + 2) * ND4];
    a3 += p[(size_t)(s + 3) * ND4];
  }
  partial4[((size_t)(b * CHUNKS + chunk)) * ND4 + fidx] = (a0 + a1) + (a2 + a3);
}

// ---------------- Kernel 2: stats + gates + sinkhorn ----------------
// grid = B (4 blocks), 1024 threads (16 waves). No atomics; shfl+LDS reductions.
__global__ __launch_bounds__(1024) void k2_stats(
    const v4f* __restrict__ partial4, const float* __restrict__ phi,
    const float* __restrict__ hpre_b, const float* __restrict__ hpost_b,
    const float* __restrict__ hres_b, const float* __restrict__ a_pre_p,
    const float* __restrict__ a_post_p, const float* __restrict__ a_res_p,
    float* __restrict__ weights) {
  int b = blockIdx.x;
  int t = threadIdx.x;
  int lane = t & 63;
  int wave = t >> 6;                 // 16 waves

  __shared__ float xs[ND];           // mean vector (already / S)
  __shared__ float wred[16];
  __shared__ float dred[16][24];
  __shared__ float dfin[24];
  __shared__ float s_inv_rms;

  // ---- Phase A: reduce CHUNKS partials -> mean vector + ssq ----
  v4f a0 = {0.f, 0.f, 0.f, 0.f};
  v4f a1 = {0.f, 0.f, 0.f, 0.f};
  const v4f* pp = partial4 + (size_t)b * CHUNKS * ND4 + t;   // t in [0,1024)
#pragma unroll 8
  for (int c = 0; c < CHUNKS; c += 2) {
    a0 += pp[(size_t)c * ND4];
    a1 += pp[(size_t)(c + 1) * ND4];
  }
  v4f a = (a0 + a1) * (1.0f / (float)S_LEN);
  xs[t * 4 + 0] = a.x; xs[t * 4 + 1] = a.y;
  xs[t * 4 + 2] = a.z; xs[t * 4 + 3] = a.w;
  float ssq = a.x * a.x + a.y * a.y + a.z * a.z + a.w * a.w;
#pragma unroll
  for (int off = 32; off; off >>= 1) ssq += __shfl_down(ssq, off, 64);
  if (lane == 0) wred[wave] = ssq;
  __syncthreads();
  if (t == 0) {
    float s = 0.f;
#pragma unroll
    for (int w = 0; w < 16; ++w) s += wred[w];
    s_inv_rms = 1.0f / sqrtf(s * (1.0f / (float)ND) + 1e-6f);
  }
  __syncthreads();

  // ---- Phase B: delta[m] = sum_i xs[i] * phi[i][m], m in [0,24) ----
  float acc[24];
#pragma unroll
  for (int m = 0; m < 24; ++m) acc[m] = 0.f;
#pragma unroll
  for (int k = 0; k < 4; ++k) {
    int i = t + k * 1024;
    float xv = xs[i];
    const float* ph = phi + (size_t)i * 24;
#pragma unroll
    for (int m = 0; m < 24; ++m) acc[m] = fmaf(xv, ph[m], acc[m]);
  }
#pragma unroll
  for (int off = 32; off; off >>= 1) {
#pragma unroll
    for (int m = 0; m < 24; ++m) acc[m] += __shfl_down(acc[m], off, 64);
  }
  if (lane == 0) {
#pragma unroll
    for (int m = 0; m < 24; ++m) dred[wave][m] = acc[m];
  }
  __syncthreads();
  if (t < 24) {
    float s = 0.f;
#pragma unroll
    for (int w = 0; w < 16; ++w) s += dred[w][t];
    dfin[t] = s * s_inv_rms;
  }
  __syncthreads();

  // ---- Phase C: gates + sinkhorn (scalar, trivial) ----
  if (t == 0) {
    float a_pre = a_pre_p[0], a_post = a_post_p[0], a_res = a_res_p[0];
    float d[24];
#pragma unroll
    for (int m = 0; m < 24; ++m) d[m] = dfin[m];

    float hp[4], hsum = 0.f;
#pragma unroll
    for (int k = 0; k < 4; ++k) {
      hp[k] = 1.0f / (1.0f + expf(-(hpre_b[k] + a_pre * d[k])));
      hsum += hp[k];
    }
    float invsum = 1.0f / (hsum + 1e-8f);
#pragma unroll
    for (int k = 0; k < 4; ++k) weights[b * 24 + k] = hp[k] * invsum;

#pragma unroll
    for (int k = 0; k < 4; ++k)
      weights[b * 24 + 4 + k] =
          1.0f / (1.0f + expf(-(hpost_b[k] + a_post * d[4 + k])));

    float P[16];
#pragma unroll
    for (int e = 0; e < 16; ++e) P[e] = expf(hres_b[e] + a_res * d[8 + e]);
    for (int it = 0; it < 20; ++it) {
#pragma unroll
      for (int i = 0; i < 4; ++i) {
        float rs = P[i * 4] + P[i * 4 + 1] + P[i * 4 + 2] + P[i * 4 + 3];
        float inv = 1.0f / (rs + 1e-6f);
        P[i * 4] *= inv; P[i * 4 + 1] *= inv; P[i * 4 + 2] *= inv; P[i * 4 + 3] *= inv;
      }
#pragma unroll
      for (int j = 0; j < 4; ++j) {
        float cs = P[j] + P[4 + j] + P[8 + j] + P[12 + j];
        float inv = 1.0f / (cs + 1e-6f);
        P[j] *= inv; P[4 + j] *= inv; P[8 + j] *= inv; P[12 + j] *= inv;
      }
    }
#pragma unroll
    for (int e = 0; e < 16; ++e) weights[b * 24 + 8 + e] = P[e];
  }
}

// ---------------- Kernel 3: apply gates ----------------
// grid = B*S = 16384 blocks, 256 threads, one float4 of D per thread.
// Non-temporal stores: out is write-once; keep L2/L3 for H.
__global__ __launch_bounds__(256) void k3_apply(const v4f* __restrict__ H4,
                                                const v4f* __restrict__ BO4,
                                                const float* __restrict__ weights,
                                                v4f* __restrict__ out4) {
  int bs = blockIdx.x;            // b * S + s
  int b = bs >> 12;
  __shared__ float w[24];
  if (threadIdx.x < 24) w[threadIdx.x] = weights[b * 24 + threadIdx.x];
  __syncthreads();
  int t = threadIdx.x;            // [0,256): float4 index within D
  const v4f* hb = H4 + (size_t)bs * ND4;
  v4f h0 = hb[t];
  v4f h1 = hb[256 + t];
  v4f h2 = hb[512 + t];
  v4f h3 = hb[768 + t];
  v4f bo = __builtin_nontemporal_load(BO4 + (size_t)bs * 256 + t);
  v4f* ob = out4 + (size_t)bs * (5 * 256);

  v4f o = w[0] * h0 + w[1] * h1 + w[2] * h2 + w[3] * h3;
  __builtin_nontemporal_store(o, ob + t);

#pragma unroll
  for (int i = 0; i < 4; ++i) {
    o = w[8 + i * 4 + 0] * h0 + w[8 + i * 4 + 1] * h1 +
        w[8 + i * 4 + 2] * h2 + w[8 + i * 4 + 3] * h3 + w[4 + i] * bo;
    __builtin_nontemporal_store(o, ob + (i + 1) * 256 + t);
  }
}

extern "C" void kernel_launch(void* const* d_in, const int* in_sizes, int n_in,
                              void* d_out, int out_size, void* d_ws, size_t ws_size,
                              hipStream_t stream) {
  const float* H       = (const float*)d_in[0];
  const float* BO      = (const float*)d_in[1];
  const float* phi     = (const float*)d_in[2];
  const float* hpre_b  = (const float*)d_in[3];
  const float* hpost_b = (const float*)d_in[4];
  const float* hres_b  = (const float*)d_in[5];
  const float* a_pre   = (const float*)d_in[6];
  const float* a_post  = (const float*)d_in[7];
  const float* a_res   = (const float*)d_in[8];
  float* out = (float*)d_out;

  const size_t partial_floats = (size_t)4 * CHUNKS * ND;  // 4 MB
  float* partial;
  float* weights;
  if (ws_size >= (partial_floats + 96) * sizeof(float)) {
    partial = (float*)d_ws;
    weights = partial + partial_floats;
  } else {
    partial = out;          // fully overwritten by k3 later
    weights = (float*)d_ws; // needs only 384 B
  }

  hipLaunchKernelGGL(k1_reduce, dim3(1024), dim3(256), 0, stream,
                     (const v4f*)H, (v4f*)partial);
  hipLaunchKernelGGL(k2_stats, dim3(4), dim3(1024), 0, stream,
                     (const v4f*)partial, phi, hpre_b, hpost_b, hres_b,
                     a_pre, a_post, a_res, weights);
  hipLaunchKernelGGL(k3_apply, dim3(4 * S_LEN), dim3(256), 0, stream,
                     (const v4f*)H, (const v4f*)BO, weights, (v4f*)out);
}